// Round 4
// baseline (652.320 us; speedup 1.0000x reference)
//
#include <hip/hip_runtime.h>
#include <stdint.h>

#define D_IN  128
#define D_OUT 64
#define BN_EPS 1e-3f
#define SCAN_BLOCKS 256

__device__ __forceinline__ ushort f32_to_bf16_rne(float f) {
  uint u = __float_as_uint(f);
  u += 0x7FFFu + ((u >> 16) & 1u);
  return (ushort)(u >> 16);
}

// ---------------- GEMM: pre16 = bf16(X @ W)  (fp32 VALU compute) ----------------
#define BM 32
#define XS_LD 132

__global__ __launch_bounds__(256) void gemm_kernel(
    const float* __restrict__ x, const float* __restrict__ W,
    ushort* __restrict__ pre16, int n_nodes) {
  __shared__ float Wl[D_IN * D_OUT];      // 32 KB
  __shared__ float xs[BM * XS_LD];        // 16.9 KB
  const int t = threadIdx.x;

  for (int i = t; i < D_IN * D_OUT; i += 256) Wl[i] = W[i];

  const int tx = t & 15;
  const int ty = t >> 4;
  const int n_tiles = (n_nodes + BM - 1) / BM;

  for (int tile = blockIdx.x; tile < n_tiles; tile += gridDim.x) {
    const int row0 = tile * BM;
    __syncthreads();
    for (int i4 = t; i4 < BM * (D_IN / 4); i4 += 256) {
      const int r = i4 >> 5;
      const int c4 = i4 & 31;
      const int row = row0 + r;
      float4 v = make_float4(0.f, 0.f, 0.f, 0.f);
      if (row < n_nodes) v = *(const float4*)&x[(size_t)row * D_IN + c4 * 4];
      *(float4*)&xs[r * XS_LD + c4 * 4] = v;
    }
    __syncthreads();

    float acc[2][4] = {};
    for (int k = 0; k < D_IN; k += 4) {
      const float4 w0 = *(const float4*)&Wl[(k + 0) * D_OUT + tx * 4];
      const float4 w1 = *(const float4*)&Wl[(k + 1) * D_OUT + tx * 4];
      const float4 w2 = *(const float4*)&Wl[(k + 2) * D_OUT + tx * 4];
      const float4 w3 = *(const float4*)&Wl[(k + 3) * D_OUT + tx * 4];
#pragma unroll
      for (int i = 0; i < 2; ++i) {
        const float4 xv = *(const float4*)&xs[(ty * 2 + i) * XS_LD + k];
        acc[i][0] += xv.x * w0.x + xv.y * w1.x + xv.z * w2.x + xv.w * w3.x;
        acc[i][1] += xv.x * w0.y + xv.y * w1.y + xv.z * w2.y + xv.w * w3.y;
        acc[i][2] += xv.x * w0.z + xv.y * w1.z + xv.z * w2.z + xv.w * w3.z;
        acc[i][3] += xv.x * w0.w + xv.y * w1.w + xv.z * w2.w + xv.w * w3.w;
      }
    }
#pragma unroll
    for (int i = 0; i < 2; ++i) {
      const int row = row0 + ty * 2 + i;
      if (row < n_nodes) {
        ushort4 o;
        o.x = f32_to_bf16_rne(acc[i][0]);
        o.y = f32_to_bf16_rne(acc[i][1]);
        o.z = f32_to_bf16_rne(acc[i][2]);
        o.w = f32_to_bf16_rne(acc[i][3]);
        *(ushort4*)&pre16[(size_t)row * D_OUT + tx * 4] = o;
      }
    }
  }
}

// ---------------- CSR build: histogram -> 3-pass scan -> fill ----------------
__global__ __launch_bounds__(256) void hist_kernel(
    const int* __restrict__ edst, int* __restrict__ counts, int n_edges) {
  const int i = blockIdx.x * 256 + threadIdx.x;
  if (i < n_edges) atomicAdd(&counts[edst[i]], 1);
}

__global__ __launch_bounds__(256) void scan_a_kernel(
    const int* __restrict__ counts, int* __restrict__ partial, int n) {
  const int b = blockIdx.x, t = threadIdx.x;
  const int seg = (n + SCAN_BLOCKS - 1) / SCAN_BLOCKS;
  const int beg = b * seg, end = min(beg + seg, n);
  const int cpt = (seg + 255) >> 8;
  const int tb = beg + t * cpt, te = min(tb + cpt, end);
  int s = 0;
  for (int i = tb; i < te; ++i) s += counts[i];
  __shared__ int ls[256];
  ls[t] = s;
  __syncthreads();
  for (int off = 128; off > 0; off >>= 1) {
    if (t < off) ls[t] += ls[t + off];
    __syncthreads();
  }
  if (t == 0) partial[b] = ls[0];
}

__global__ __launch_bounds__(256) void scan_b_kernel(int* __restrict__ partial) {
  const int t = threadIdx.x;
  __shared__ int ls[256];
  const int v = partial[t];
  ls[t] = v;
  __syncthreads();
  for (int off = 1; off < 256; off <<= 1) {
    const int u = (t >= off) ? ls[t - off] : 0;
    __syncthreads();
    ls[t] += u;
    __syncthreads();
  }
  partial[t] = ls[t] - v;  // exclusive
}

// pass C: write offsets AND cursor (copy); counts stay as degrees
__global__ __launch_bounds__(256) void scan_c_kernel(
    const int* __restrict__ counts, int* __restrict__ offsets,
    int* __restrict__ cursor, const int* __restrict__ partial, int n) {
  const int b = blockIdx.x, t = threadIdx.x;
  const int seg = (n + SCAN_BLOCKS - 1) / SCAN_BLOCKS;
  const int beg = b * seg, end = min(beg + seg, n);
  const int cpt = (seg + 255) >> 8;
  const int tb = beg + t * cpt, te = min(tb + cpt, end);
  int s = 0;
  for (int i = tb; i < te; ++i) s += counts[i];
  __shared__ int ls[256];
  ls[t] = s;
  __syncthreads();
  for (int off = 1; off < 256; off <<= 1) {
    const int u = (t >= off) ? ls[t - off] : 0;
    __syncthreads();
    ls[t] += u;
    __syncthreads();
  }
  int run = partial[b] + ls[t] - s;
  for (int i = tb; i < te; ++i) {
    offsets[i] = run;
    cursor[i] = run;
    run += counts[i];
  }
}

// fill: one fused atomic gives the slot; 4B packed record (val_bf15 << 17 | src)
__global__ __launch_bounds__(256) void fill_kernel(
    const float* __restrict__ ev, const int* __restrict__ esrc,
    const int* __restrict__ edst, int* __restrict__ cursor,
    uint* __restrict__ bucket, int n_edges) {
  const int i = blockIdx.x * 256 + threadIdx.x;
  if (i >= n_edges) return;
  const int dst = edst[i];
  const int pos = atomicAdd(&cursor[dst], 1);
  const uint b15 = (uint)f32_to_bf16_rne(ev[i]);  // val >= 0 -> sign bit 0
  bucket[pos] = (b15 << 17) | (uint)esrc[i];
}

// ---------------- Gather: one 64-lane wave per dst node ----------------
__device__ __forceinline__ float unpack_val(uint r) {
  return __uint_as_float((r >> 17) << 16);
}
__device__ __forceinline__ float pre_at(const ushort* __restrict__ pre16,
                                        uint r, int lane) {
  const uint src = r & 0x1FFFFu;
  return __uint_as_float((uint)pre16[(size_t)src * D_OUT + lane] << 16);
}

__global__ __launch_bounds__(256) void gather_kernel(
    const ushort* __restrict__ pre16, const uint* __restrict__ bucket,
    const int* __restrict__ offsets, const int* __restrict__ counts,
    float* __restrict__ out, int n_nodes) {
  const int node = blockIdx.x * 4 + (threadIdx.x >> 6);
  if (node >= n_nodes) return;
  const int lane = threadIdx.x & 63;
  const int beg = offsets[node];
  const int deg = counts[node];
  float a0 = 0.f, a1 = 0.f, a2 = 0.f, a3 = 0.f;
  int j = 0;
  for (; j + 3 < deg; j += 4) {
    const uint r0 = bucket[beg + j];
    const uint r1 = bucket[beg + j + 1];
    const uint r2 = bucket[beg + j + 2];
    const uint r3 = bucket[beg + j + 3];
    a0 += unpack_val(r0) * pre_at(pre16, r0, lane);
    a1 += unpack_val(r1) * pre_at(pre16, r1, lane);
    a2 += unpack_val(r2) * pre_at(pre16, r2, lane);
    a3 += unpack_val(r3) * pre_at(pre16, r3, lane);
  }
  for (; j < deg; ++j) {
    const uint r = bucket[beg + j];
    a0 += unpack_val(r) * pre_at(pre16, r, lane);
  }
  out[(size_t)node * D_OUT + lane] = (a0 + a1) + (a2 + a3);
}

// ---------------- BN stats ----------------
__global__ __launch_bounds__(256) void stats_kernel(
    const float* __restrict__ out, float* __restrict__ stats, int64_t n_elems) {
  float s = 0.f, s2 = 0.f;
  const int64_t stride = (int64_t)gridDim.x * 256;
  for (int64_t i = (int64_t)blockIdx.x * 256 + threadIdx.x; i < n_elems;
       i += stride) {
    const float v = out[i];
    s += v;
    s2 += v * v;
  }
  __shared__ float ls[256], ls2[256];
  const int t = threadIdx.x;
  ls[t] = s;
  ls2[t] = s2;
  __syncthreads();
  if (t < 128) { ls[t] += ls[t + 128]; ls2[t] += ls2[t + 128]; }
  __syncthreads();
  if (t < 64) {
    atomicAdd(&stats[t], ls[t] + ls[t + 64]);
    atomicAdd(&stats[64 + t], ls2[t] + ls2[t + 64]);
  }
}

// ---------------- Normalize + ReLU (in place) ----------------
__global__ __launch_bounds__(256) void norm_kernel(
    float* __restrict__ out, const float* __restrict__ stats, int64_t n_elems,
    float inv_n) {
  const int c = threadIdx.x & 63;
  const float mean = stats[c] * inv_n;
  const float var = stats[64 + c] * inv_n - mean * mean;
  const float scale = rsqrtf(var + BN_EPS);
  const int64_t stride = (int64_t)gridDim.x * 256;
  for (int64_t i = (int64_t)blockIdx.x * 256 + threadIdx.x; i < n_elems;
       i += stride) {
    const float v = (out[i] - mean) * scale;
    out[i] = v > 0.f ? v : 0.f;
  }
}

// ---------------- launch ----------------
extern "C" void kernel_launch(void* const* d_in, const int* in_sizes, int n_in,
                              void* d_out, int out_size, void* d_ws,
                              size_t ws_size, hipStream_t stream) {
  const float* x = (const float*)d_in[0];
  const float* W = (const float*)d_in[1];
  const float* ev = (const float*)d_in[2];
  const int* esrc = (const int*)d_in[3];
  const int* edst = (const int*)d_in[4];

  const int n_nodes = in_sizes[0] / D_IN;
  const int n_edges = in_sizes[2];
  const int64_t n_out = (int64_t)n_nodes * D_OUT;

  float* out = (float*)d_out;

  // workspace layout
  char* w = (char*)d_ws;
  ushort* pre16 = (ushort*)w;             w += (size_t)n_nodes * D_OUT * 2;
  int* counts = (int*)w;                  w += (size_t)n_nodes * 4;
  int* offsets = (int*)w;                 w += (size_t)n_nodes * 4;
  int* cursor = (int*)w;                  w += (size_t)n_nodes * 4;
  int* partial = (int*)w;                 w += SCAN_BLOCKS * 4;
  float* stats = (float*)w;               w += 128 * 4;
  w = (char*)(((uintptr_t)w + 7) & ~(uintptr_t)7);
  uint* bucket = (uint*)w;                // n_edges * 4 bytes

  hipMemsetAsync(counts, 0, (size_t)n_nodes * 4, stream);
  hipMemsetAsync(stats, 0, 128 * 4, stream);

  const int eblocks = (n_edges + 255) / 256;
  gemm_kernel<<<2048, 256, 0, stream>>>(x, W, pre16, n_nodes);
  hist_kernel<<<eblocks, 256, 0, stream>>>(edst, counts, n_edges);
  scan_a_kernel<<<SCAN_BLOCKS, 256, 0, stream>>>(counts, partial, n_nodes);
  scan_b_kernel<<<1, 256, 0, stream>>>(partial);
  scan_c_kernel<<<SCAN_BLOCKS, 256, 0, stream>>>(counts, offsets, cursor,
                                                 partial, n_nodes);
  fill_kernel<<<eblocks, 256, 0, stream>>>(ev, esrc, edst, cursor, bucket,
                                           n_edges);
  gather_kernel<<<(n_nodes + 3) / 4, 256, 0, stream>>>(pre16, bucket, offsets,
                                                       counts, out, n_nodes);
  stats_kernel<<<1024, 256, 0, stream>>>(out, stats, n_out);
  norm_kernel<<<2048, 256, 0, stream>>>(out, stats, n_out,
                                        1.0f / (float)n_nodes);
}